// Round 11
// baseline (64.892 us; speedup 1.0000x reference)
//
#include <hip/hip_runtime.h>
#include <stdint.h>

// (N,T,F)=(128,8192,8), WS=16, E=256 -> nw=512, keep=205, mask=307
#define NB     128
#define TLEN   8192
#define FD     8
#define KD     128          // WS*F (GEMM K)
#define NWIN   512
#define ED     256
#define NKEEP  205
#define NMASK  307

// float32-element offsets in the concatenated output tuple
#define OFF_VIS  0UL
#define OFF_TGT  6717440UL        // + 128*205*256
#define OFF_MSK  16777216UL       // + 128*307*256
#define OFF_VIDX 26836992UL       // + 128*307*256
#define OFF_MIDX 26863232UL       // + 128*205

#define ESTRIDE 260   // float stride of Ebuf row (256 + 4 pad -> 2-way banks on write)

typedef __attribute__((ext_vector_type(8))) short bf16x8;
typedef __attribute__((ext_vector_type(4))) float f32x4;
typedef __attribute__((ext_vector_type(4))) unsigned int u32x4;

static __device__ __forceinline__ unsigned short f2bf(float x) {
  union { float f; unsigned int u; } v; v.f = x;
  unsigned int r = v.u + 0x7fffu + ((v.u >> 16) & 1u);   // RNE
  return (unsigned short)(r >> 16);
}
static __device__ __forceinline__ unsigned int pack2(float a, float b) {
  return (unsigned int)f2bf(a) | ((unsigned int)f2bf(b) << 16);
}

// Pre-convert W (256x128 f32) to bf16 in workspace (64 KB, L2-resident after).
__global__ __launch_bounds__(256) void convw_kernel(
    const float* __restrict__ W, unsigned short* __restrict__ wbf)
{
  const int i = blockIdx.x * 256 + threadIdx.x;   // 4096 threads, 8 floats each
  const float* s = W + (size_t)i * 8;
  const f32x4 v0 = *(const f32x4*)s;
  const f32x4 v1 = *(const f32x4*)(s + 4);
  u32x4 pk;
  pk[0] = pack2(v0[0], v0[1]); pk[1] = pack2(v0[2], v0[3]);
  pk[2] = pack2(v1[0], v1[1]); pk[3] = pack2(v1[2], v1[3]);
  *(u32x4*)(wbf + (size_t)i * 8) = pk;
}

// Wave-independent fused kernel: 1 workgroup = 1 wave (64 thr) = 16 slots x
// ALL 256 features. No barriers, no cross-wave coupling. A-rows gathered once,
// W frags re-read per j-tile from bf16 workspace (L2). Epilogue transposes
// through a private Ebuf (lgkmcnt-only) and stores FULL 1KB rows per
// instruction (vis/tgt, and msk = mask_token + pos for masked slots).
__global__ __launch_bounds__(64, 3) void fused_wave(
    const float* __restrict__ temps, const unsigned short* __restrict__ wbf,
    const float* __restrict__ Wf32,
    const float* __restrict__ b, const float* __restrict__ mask_token,
    const float* __restrict__ pos, const int* __restrict__ perm,
    float* __restrict__ out)
{
  __shared__ __align__(16) float Ebuf[16][ESTRIDE];

  const int lane = threadIdx.x;
  const int l15  = lane & 15;
  const int lhi  = lane >> 4;    // 0..3

  const int n  = blockIdx.x >> 5;          // 32 tiles per batch row
  const int s0 = (blockIdx.x & 31) * 16;

  // per-lane perm (lane l15 = slot row; lhi groups duplicate/broadcast)
  const int Pv = perm[n * NWIN + s0 + l15] & (NWIN - 1);
  const f32x4 b4  = *(const f32x4*)&b[lane * 4];
  const f32x4 mt4 = *(const f32x4*)&mask_token[lane * 4];

  // ---- A fragments: gathered row, 8x16B loads issued up front ----
  const float* arow = temps + (size_t)n * (TLEN * FD) + (size_t)Pv * KD + lhi * 8;
  f32x4 av[8];
  #pragma unroll
  for (int kk = 0; kk < 4; ++kk) {
    av[2 * kk]     = *(const f32x4*)(arow + kk * 32);
    av[2 * kk + 1] = *(const f32x4*)(arow + kk * 32 + 4);
  }
  bf16x8 a[4];
  #pragma unroll
  for (int kk = 0; kk < 4; ++kk) {
    bf16x8 f;
    const f32x4 lo = av[2 * kk], hi = av[2 * kk + 1];
    f[0] = (short)f2bf(lo[0]); f[1] = (short)f2bf(lo[1]);
    f[2] = (short)f2bf(lo[2]); f[3] = (short)f2bf(lo[3]);
    f[4] = (short)f2bf(hi[0]); f[5] = (short)f2bf(hi[1]);
    f[6] = (short)f2bf(hi[2]); f[7] = (short)f2bf(hi[3]);
    a[kk] = f;
  }

  // ---- GEMM: j-outer (16 feature tiles), kk-inner; W frags from L2 ----
  const f32x4 zero = {0.f, 0.f, 0.f, 0.f};
  f32x4 acc[16];
  #pragma unroll
  for (int j = 0; j < 16; ++j) acc[j] = zero;

  if (wbf) {
    #pragma unroll
    for (int j = 0; j < 16; ++j) {
      const unsigned short* wrow = wbf + (size_t)(j * 16 + l15) * KD + lhi * 8;
      const bf16x8 w0 = *(const bf16x8*)(wrow);
      const bf16x8 w1 = *(const bf16x8*)(wrow + 32);
      const bf16x8 w2 = *(const bf16x8*)(wrow + 64);
      const bf16x8 w3 = *(const bf16x8*)(wrow + 96);
      acc[j] = __builtin_amdgcn_mfma_f32_16x16x32_bf16(a[0], w0, acc[j], 0, 0, 0);
      acc[j] = __builtin_amdgcn_mfma_f32_16x16x32_bf16(a[1], w1, acc[j], 0, 0, 0);
      acc[j] = __builtin_amdgcn_mfma_f32_16x16x32_bf16(a[2], w2, acc[j], 0, 0, 0);
      acc[j] = __builtin_amdgcn_mfma_f32_16x16x32_bf16(a[3], w3, acc[j], 0, 0, 0);
    }
  } else {
    #pragma unroll
    for (int j = 0; j < 16; ++j) {
      const float* wrow = Wf32 + (size_t)(j * 16 + l15) * KD + lhi * 8;
      #pragma unroll
      for (int kk = 0; kk < 4; ++kk) {
        const f32x4 lo = *(const f32x4*)(wrow + kk * 32);
        const f32x4 hi = *(const f32x4*)(wrow + kk * 32 + 4);
        bf16x8 f;
        f[0] = (short)f2bf(lo[0]); f[1] = (short)f2bf(lo[1]);
        f[2] = (short)f2bf(lo[2]); f[3] = (short)f2bf(lo[3]);
        f[4] = (short)f2bf(hi[0]); f[5] = (short)f2bf(hi[1]);
        f[6] = (short)f2bf(hi[2]); f[7] = (short)f2bf(hi[3]);
        acc[j] = __builtin_amdgcn_mfma_f32_16x16x32_bf16(a[kk], f, acc[j], 0, 0, 0);
      }
    }
  }

  // ---- transpose via private Ebuf (single wave: lgkmcnt only, no barrier) ----
  // acc[j][r]: slot row = lhi*4 + r, feature = j*16 + l15
  #pragma unroll
  for (int j = 0; j < 16; ++j)
    #pragma unroll
    for (int r = 0; r < 4; ++r)
      Ebuf[lhi * 4 + r][j * 16 + l15] = acc[j][r];
  __asm__ volatile("s_waitcnt lgkmcnt(0)" ::: "memory");

  // ---- epilogue: full-1KB-row stores ----
  #pragma unroll
  for (int sr = 0; sr < 16; ++sr) {
    const int slot = s0 + sr;
    const int wr   = __shfl(Pv, sr);
    f32x4 v = *(const f32x4*)&Ebuf[sr][lane * 4];
    const f32x4 pz = *(const f32x4*)&pos[(size_t)wr * ED + lane * 4];
    v = v + b4 + pz;
    if (slot < NKEEP) {
      *(f32x4*)&out[OFF_VIS + (size_t)(n * NKEEP + slot) * ED + lane * 4] = v;
    } else {
      const int ms = slot - NKEEP;
      *(f32x4*)&out[OFF_TGT + (size_t)(n * NMASK + ms) * ED + lane * 4] = v;
      *(f32x4*)&out[OFF_MSK + (size_t)(n * NMASK + ms) * ED + lane * 4] = mt4 + pz;
    }
  }

  // idx outputs: lanes 0..15 store all 16 values in one pass
  if (lhi == 0) {
    const int slot = s0 + l15;
    if (slot < NKEEP) out[OFF_VIDX + (size_t)n * NKEEP + slot] = (float)Pv;
    else              out[OFF_MIDX + (size_t)n * NMASK + (slot - NKEEP)] = (float)Pv;
  }
}

extern "C" void kernel_launch(void* const* d_in, const int* in_sizes, int n_in,
                              void* d_out, int out_size, void* d_ws, size_t ws_size,
                              hipStream_t stream) {
  int i_temps = 0, i_W = 1, i_b = 2, i_mt = 3, i_pos = 4, i_perm = 5;
  int small[2] = {-1, -1}; int nsmall = 0;
  for (int i = 0; i < n_in; ++i) {
    const int s = in_sizes[i];
    if (s == NB * TLEN * FD)        i_temps = i;
    else if (s == ED * KD)          i_W = i;
    else if (s == 1024 * ED)        i_pos = i;
    else if (s == NB * NWIN)        i_perm = i;
    else if (s == ED && nsmall < 2) small[nsmall++] = i;
  }
  if (nsmall == 2) { i_b = small[0]; i_mt = small[1]; }

  const float* temps      = (const float*)d_in[i_temps];
  const float* W          = (const float*)d_in[i_W];
  const float* b          = (const float*)d_in[i_b];
  const float* mask_token = (const float*)d_in[i_mt];
  const float* pos        = (const float*)d_in[i_pos];
  const int*   perm       = (const int*)d_in[i_perm];
  float* out = (float*)d_out;

  unsigned short* wbf = (ws_size >= (size_t)(ED * KD * 2)) ? (unsigned short*)d_ws
                                                           : nullptr;
  if (wbf)
    convw_kernel<<<dim3(ED * KD / 8 / 256), dim3(256), 0, stream>>>(W, wbf);

  fused_wave<<<dim3(NB * 32), dim3(64), 0, stream>>>(
      temps, wbf, W, b, mask_token, pos, perm, out);
}

// Round 12
// 41.054 us; speedup vs baseline: 1.5807x; 1.5807x over previous
//
#include <hip/hip_runtime.h>
#include <stdint.h>

// (N,T,F)=(128,8192,8), WS=16, E=256 -> nw=512, keep=205, mask=307
#define NB     128
#define TLEN   8192
#define FD     8
#define KD     128          // WS*F (GEMM K)
#define NWIN   512
#define ED     256
#define NKEEP  205
#define NMASK  307

// float32-element offsets in the concatenated output tuple
#define OFF_VIS  0UL
#define OFF_TGT  6717440UL        // + 128*205*256
#define OFF_MSK  16777216UL       // + 128*307*256
#define OFF_VIDX 26836992UL       // + 128*307*256
#define OFF_MIDX 26863232UL       // + 128*205

#define SLOTS   32    // slots per block (2 MFMA tiles)
#define ASTRIDE 136   // ushort per A row (128 + 8 pad)
#define ESTRIDE 68    // float per E row (64 + 4 pad)

typedef __attribute__((ext_vector_type(8))) short bf16x8;
typedef __attribute__((ext_vector_type(4))) float f32x4;
typedef __attribute__((ext_vector_type(4))) unsigned int u32x4;

static __device__ __forceinline__ unsigned short f2bf(float x) {
  union { float f; unsigned int u; } v; v.f = x;
  unsigned int r = v.u + 0x7fffu + ((v.u >> 16) & 1u);   // RNE
  return (unsigned short)(r >> 16);
}
static __device__ __forceinline__ unsigned int pack2(float a, float b) {
  return (unsigned int)f2bf(a) | ((unsigned int)f2bf(b) << 16);
}

// lgkm-only barrier: LDS ordering without draining global stores.
static __device__ __forceinline__ void lds_barrier() {
  __asm__ volatile("s_waitcnt lgkmcnt(0)" ::: "memory");
  __builtin_amdgcn_s_barrier();
}

// non-temporal 16B store: no-allocate hint keeps 106MB of streamed output
// from evicting the read-side working set (W/pos/temps) in L2/L3.
static __device__ __forceinline__ void nt_store(float* p, f32x4 v) {
  __builtin_nontemporal_store(v, (f32x4*)p);
}

// Pre-convert W (256x128 f32) to bf16 in workspace.
__global__ __launch_bounds__(256) void convw_kernel(
    const float* __restrict__ W, unsigned short* __restrict__ wbf)
{
  const int i = blockIdx.x * 256 + threadIdx.x;   // 4096 threads, 8 floats each
  const float* s = W + (size_t)i * 8;
  const f32x4 v0 = *(const f32x4*)s;
  const f32x4 v1 = *(const f32x4*)(s + 4);
  u32x4 pk;
  pk[0] = pack2(v0[0], v0[1]); pk[1] = pack2(v0[2], v0[3]);
  pk[2] = pack2(v1[0], v1[1]); pk[3] = pack2(v1[2], v1[3]);
  *(u32x4*)(wbf + (size_t)i * 8) = pk;
}

// r10 structure exactly; only the bulk output stores are non-temporal.
__global__ __launch_bounds__(256, 3) void fused2_kernel(
    const float* __restrict__ temps, const unsigned short* __restrict__ wbf,
    const float* __restrict__ Wf32,
    const float* __restrict__ b, const float* __restrict__ mask_token,
    const float* __restrict__ pos, const int* __restrict__ perm,
    float* __restrict__ out)
{
  __shared__ __align__(16) unsigned short Abuf[SLOTS][ASTRIDE];
  __shared__ __align__(16) float Ebuf[4][16][ESTRIDE];
  __shared__ int Pbuf[SLOTS];

  const int tid  = threadIdx.x;
  const int lane = tid & 63;
  const int wv   = tid >> 6;     // 0..3
  const int l15  = lane & 15;
  const int lhi  = lane >> 4;    // 0..3

  const int n  = blockIdx.x >> 4;          // 16 blocks per batch row
  const int s0 = (blockIdx.x & 15) * SLOTS;
  const int e0 = wv * 64;

  if (tid < SLOTS) Pbuf[tid] = perm[n * NWIN + s0 + tid] & (NWIN - 1);

  // W fragments (b-operand: lane l15 = feature col e0+j*16+l15, elems -> k)
  bf16x8 wb[4][4];
  float  bb[4];
  if (wbf) {
    #pragma unroll
    for (int j = 0; j < 4; ++j) {
      const unsigned short* wrow = wbf + (size_t)(e0 + j * 16 + l15) * KD + lhi * 8;
      #pragma unroll
      for (int kk = 0; kk < 4; ++kk)
        wb[j][kk] = *(const bf16x8*)(wrow + kk * 32);
    }
  } else {
    #pragma unroll
    for (int j = 0; j < 4; ++j) {
      const float* wrow = Wf32 + (size_t)(e0 + j * 16 + l15) * KD + lhi * 8;
      #pragma unroll
      for (int kk = 0; kk < 4; ++kk) {
        f32x4 w0 = *(const f32x4*)(wrow + kk * 32);
        f32x4 w1 = *(const f32x4*)(wrow + kk * 32 + 4);
        bf16x8 f;
        f[0] = (short)f2bf(w0[0]); f[1] = (short)f2bf(w0[1]);
        f[2] = (short)f2bf(w0[2]); f[3] = (short)f2bf(w0[3]);
        f[4] = (short)f2bf(w1[0]); f[5] = (short)f2bf(w1[1]);
        f[6] = (short)f2bf(w1[2]); f[7] = (short)f2bf(w1[3]);
        wb[j][kk] = f;
      }
    }
  }
  #pragma unroll
  for (int j = 0; j < 4; ++j) bb[j] = b[e0 + j * 16 + l15];
  const f32x4 mt4 = *(const f32x4*)&mask_token[e0 + l15 * 4];

  const float* tbase = temps + (size_t)n * (TLEN * FD);
  const int srow = tid >> 4;     // 0..15
  const int sseg = tid & 15;     // 8-float segment

  lds_barrier();   // Pbuf ready

  // stage all 32 rows (2 rows per thread)
  {
    const float* p0 = tbase + (size_t)Pbuf[srow] * KD + sseg * 8;
    const float* p1 = tbase + (size_t)Pbuf[srow + 16] * KD + sseg * 8;
    const f32x4 a0 = *(const f32x4*)p0;
    const f32x4 a1 = *(const f32x4*)(p0 + 4);
    const f32x4 c0 = *(const f32x4*)p1;
    const f32x4 c1 = *(const f32x4*)(p1 + 4);
    u32x4 pk;
    pk[0] = pack2(a0[0], a0[1]); pk[1] = pack2(a0[2], a0[3]);
    pk[2] = pack2(a1[0], a1[1]); pk[3] = pack2(a1[2], a1[3]);
    *(u32x4*)&Abuf[srow][sseg * 8] = pk;
    pk[0] = pack2(c0[0], c0[1]); pk[1] = pack2(c0[2], c0[3]);
    pk[2] = pack2(c1[0], c1[1]); pk[3] = pack2(c1[2], c1[3]);
    *(u32x4*)&Abuf[srow + 16][sseg * 8] = pk;
  }
  lds_barrier();   // Abuf ready

  const f32x4 zero = {0.f, 0.f, 0.f, 0.f};

  #pragma unroll
  for (int t = 0; t < 2; ++t) {
    // acc[j][r] = emb[slot = lhi*4+r][feature = e0+j*16+l15]
    f32x4 acc[4];
    acc[0] = zero; acc[1] = zero; acc[2] = zero; acc[3] = zero;
    #pragma unroll
    for (int kk = 0; kk < 4; ++kk) {
      const bf16x8 a = *(const bf16x8*)&Abuf[t * 16 + l15][kk * 32 + lhi * 8];
      #pragma unroll
      for (int j = 0; j < 4; ++j)
        acc[j] = __builtin_amdgcn_mfma_f32_16x16x32_bf16(a, wb[j][kk], acc[j], 0, 0, 0);
    }

    // per-wave Ebuf transpose -> coalesced stores (no cross-wave barrier)
    #pragma unroll
    for (int j = 0; j < 4; ++j)
      #pragma unroll
      for (int r = 0; r < 4; ++r)
        Ebuf[wv][lhi * 4 + r][j * 16 + l15] = acc[j][r] + bb[j];
    __asm__ volatile("s_waitcnt lgkmcnt(0)" ::: "memory");
    #pragma unroll
    for (int g = 0; g < 4; ++g) {
      const int sr   = g * 4 + lhi;
      const int slot = s0 + t * 16 + sr;
      const int wr   = Pbuf[t * 16 + sr];
      f32x4 v = *(const f32x4*)&Ebuf[wv][sr][l15 * 4];
      const f32x4 pz = *(const f32x4*)&pos[(size_t)wr * ED + e0 + l15 * 4];
      v = v + pz;
      if (slot < NKEEP) {
        nt_store(&out[OFF_VIS + (size_t)(n * NKEEP + slot) * ED + e0 + l15 * 4], v);
        if (l15 == 0 && wv == 0)
          out[OFF_VIDX + (size_t)n * NKEEP + slot] = (float)wr;
      } else {
        const int ms = slot - NKEEP;
        nt_store(&out[OFF_TGT + (size_t)(n * NMASK + ms) * ED + e0 + l15 * 4], v);
        nt_store(&out[OFF_MSK + (size_t)(n * NMASK + ms) * ED + e0 + l15 * 4], mt4 + pz);
        if (l15 == 0 && wv == 0)
          out[OFF_MIDX + (size_t)n * NMASK + ms] = (float)wr;
      }
    }
  }
}

extern "C" void kernel_launch(void* const* d_in, const int* in_sizes, int n_in,
                              void* d_out, int out_size, void* d_ws, size_t ws_size,
                              hipStream_t stream) {
  int i_temps = 0, i_W = 1, i_b = 2, i_mt = 3, i_pos = 4, i_perm = 5;
  int small[2] = {-1, -1}; int nsmall = 0;
  for (int i = 0; i < n_in; ++i) {
    const int s = in_sizes[i];
    if (s == NB * TLEN * FD)        i_temps = i;
    else if (s == ED * KD)          i_W = i;
    else if (s == 1024 * ED)        i_pos = i;
    else if (s == NB * NWIN)        i_perm = i;
    else if (s == ED && nsmall < 2) small[nsmall++] = i;
  }
  if (nsmall == 2) { i_b = small[0]; i_mt = small[1]; }

  const float* temps      = (const float*)d_in[i_temps];
  const float* W          = (const float*)d_in[i_W];
  const float* b          = (const float*)d_in[i_b];
  const float* mask_token = (const float*)d_in[i_mt];
  const float* pos        = (const float*)d_in[i_pos];
  const int*   perm       = (const int*)d_in[i_perm];
  float* out = (float*)d_out;

  unsigned short* wbf = (ws_size >= (size_t)(ED * KD * 2)) ? (unsigned short*)d_ws
                                                           : nullptr;
  if (wbf)
    convw_kernel<<<dim3(ED * KD / 8 / 256), dim3(256), 0, stream>>>(W, wbf);

  fused2_kernel<<<dim3(NB * 16), dim3(256), 0, stream>>>(
      temps, wbf, W, b, mask_token, pos, perm, out);
}